// Round 7
// baseline (742.205 us; speedup 1.0000x reference)
//
#include <hip/hip_runtime.h>
#include <math.h>

#define B_   128
#define R_   1152
#define RS_  64
#define RCH_ 18            // R_/RS_
#define NBINS 72           // 1152/16 colsum bins
#define GRID_ 512

// ws float offsets (R6 layout)
#define WS_SP   0          // RS_*32768 = 2097152
#define WS_V    2097152    // 32768
#define WS_BLOG 2129920    // 18432
#define WS_CTRL 2148352    // 2560 floats: cs0 @+0 (72*16), cs1 @+1280, barriers @+2432
#define WS_WT   2150912    // 2359296 (Wt4[r*512 + d*64 + co4])

__device__ __forceinline__ float squashf(float s) {
    return s * fabsf(s) / (1.0f + s * s);
}

// ---------- Z: zero colsum bins + barrier counters (must precede caps_all_k)
__global__ __launch_bounds__(256) void zero_k(float* __restrict__ ctrl) {
    for (int u = threadIdx.x; u < 2560; u += 256) ctrl[u] = 0.0f;
}

// device-wide barrier: distinct pre-zeroed counter per phase (no reset/wrap).
// Release: threadfence + atomicAdd; acquire: spin (agent-scope) + threadfence.
// Safe: all GRID_ blocks co-resident (512 blocks, >=4 blocks/CU capacity).
__device__ __forceinline__ void gbar(unsigned int* __restrict__ bar, int ph) {
    __syncthreads();
    if (threadIdx.x == 0) {
        __threadfence();
        atomicAdd(&bar[ph * 16], 1u);
        while (__hip_atomic_load(&bar[ph * 16], __ATOMIC_RELAXED,
                                 __HIP_MEMORY_SCOPE_AGENT) < (unsigned int)GRID_)
            __builtin_amdgcn_s_sleep(1);
    }
    __syncthreads();
    __threadfence();
}

// ---------- fused persistent kernel: T -> [G -> R -> A]x3 (A skipped on it==2)
__global__ __launch_bounds__(256, 3) void caps_all_k(
        const float* __restrict__ x, const float* __restrict__ W,
        float* __restrict__ wt, float* __restrict__ sp,
        float* __restrict__ v, float* __restrict__ blog,
        float* __restrict__ ctrl, float* __restrict__ out)
{
    const int bid = blockIdx.x;
    const int t   = threadIdx.x;

    __shared__ float4 xl4[576];        // G: x tile (also T: transpose scratch, 520<=576)
    __shared__ float  cwl[288];
    __shared__ float  colinv_sh[16];
    __shared__ float  psum[256];
    __shared__ float  redr[256];
    __shared__ float4 xla[256];        // A: x column
    __shared__ float  reda[64];

    const float4* __restrict__ X4 = (const float4*)x;
    const float4* __restrict__ W4 = (const float4*)W;
    float4* __restrict__ Wt4 = (float4*)wt;
    unsigned int* bar = (unsigned int*)(ctrl + 2432);   // 8 counters, 64B apart
    float* cs0 = ctrl;
    float* cs1 = ctrl + 1280;

    // ---- T: Wt4[r*512 + d*64 + co4] = W4[r*512 + co4*8 + d] (pitch-65 swizzle)
    {
        float4* sh = xl4;
        for (int r = bid; r < R_; r += GRID_) {
            #pragma unroll
            for (int k = 0; k < 2; ++k) {
                const int u = t + k * 256;            // u = co4*8 + d
                sh[(u & 7) * 65 + (u >> 3)] = W4[r * 512 + u];
            }
            __syncthreads();
            #pragma unroll
            for (int k = 0; k < 2; ++k) {
                const int u = t + k * 256;            // u = d*64 + co4
                Wt4[r * 512 + u] = sh[(u >> 6) * 65 + (u & 63)];
            }
            __syncthreads();
        }
    }
    gbar(bar, 0);

    for (int it = 0; it < 3; ++it) {
        // ================= G: sp[rs][b][co] =================
        {
            const int bt = bid & 7, rs = bid >> 3;    // R0's dim3(8,64) mapping
            const int co4 = t & 63, b4 = t >> 6, c = co4 >> 2;
            const int r0 = rs * RCH_;

            #pragma unroll
            for (int k = 0; k < 3; ++k) {
                const int u = t + k * 256;
                if (u < 576) {
                    const int bl = u / 36, rem = u % 36;
                    xl4[u] = X4[((bt * 16 + bl) * R_ + r0) * 2 + rem];
                }
            }
            if (it == 0) {
                for (int u2 = t; u2 < 288; u2 += 256) cwl[u2] = 1.0f / (float)R_;
            } else {
                const float* colbins = (it == 1) ? cs0 : cs1;
                const int cc = t & 15, jb = t >> 4;
                float s = 0.f;
                for (int j = jb; j < NBINS; j += 16) s += colbins[j * 16 + cc];
                psum[t] = s;
                __syncthreads();
                if (t < 16) {
                    float tot = 0.f;
                    #pragma unroll
                    for (int k2 = 0; k2 < 16; ++k2) tot += psum[k2 * 16 + t];
                    colinv_sh[t] = 1.0f / tot;
                }
                __syncthreads();
                for (int u2 = t; u2 < 288; u2 += 256) {
                    const int rl = u2 >> 4, c2 = u2 & 15;
                    cwl[u2] = __expf(blog[(r0 + rl) * 16 + c2]) * colinv_sh[c2];
                }
            }
            __syncthreads();

            float acc[4][4];
            #pragma unroll
            for (int j = 0; j < 4; ++j)
                #pragma unroll
                for (int q = 0; q < 4; ++q) acc[j][q] = 0.f;

            #pragma unroll 3
            for (int rr = 0; rr < RCH_; ++rr) {
                const float cwv = cwl[rr * 16 + c];
                const float4* wp = (const float4*)wt + ((size_t)(r0 + rr) << 9) + co4;
                const float4 w0 = wp[  0], w1 = wp[ 64], w2 = wp[128], w3 = wp[192];
                const float4 w4 = wp[256], w5 = wp[320], w6 = wp[384], w7 = wp[448];
                #pragma unroll
                for (int j = 0; j < 4; ++j) {
                    const float4 xa = xl4[(b4 * 4 + j) * 36 + rr * 2];
                    const float4 xb = xl4[(b4 * 4 + j) * 36 + rr * 2 + 1];
                    const float d0 = w0.x*xa.x + w0.y*xa.y + w0.z*xa.z + w0.w*xa.w
                                   + w1.x*xb.x + w1.y*xb.y + w1.z*xb.z + w1.w*xb.w;
                    const float d1 = w2.x*xa.x + w2.y*xa.y + w2.z*xa.z + w2.w*xa.w
                                   + w3.x*xb.x + w3.y*xb.y + w3.z*xb.z + w3.w*xb.w;
                    const float d2 = w4.x*xa.x + w4.y*xa.y + w4.z*xa.z + w4.w*xa.w
                                   + w5.x*xb.x + w5.y*xb.y + w5.z*xb.z + w5.w*xb.w;
                    const float d3 = w6.x*xa.x + w6.y*xa.y + w6.z*xa.z + w6.w*xa.w
                                   + w7.x*xb.x + w7.y*xb.y + w7.z*xb.z + w7.w*xb.w;
                    acc[j][0] = fmaf(cwv, d0, acc[j][0]);
                    acc[j][1] = fmaf(cwv, d1, acc[j][1]);
                    acc[j][2] = fmaf(cwv, d2, acc[j][2]);
                    acc[j][3] = fmaf(cwv, d3, acc[j][3]);
                }
            }

            float4* sp4 = (float4*)sp;
            #pragma unroll
            for (int j = 0; j < 4; ++j) {
                const int b = bt * 16 + b4 * 4 + j;
                float4 o4; o4.x = acc[j][0]; o4.y = acc[j][1];
                o4.z = acc[j][2]; o4.w = acc[j][3];
                sp4[(rs * B_ + b) * 64 + co4] = o4;
            }
        }
        gbar(bar, it * 3 + 1);

        // ================= R: v/out = squash(sum_k sp) =================
        {
            const int li = t & 63, kq = t >> 6;       // 4-way k-split of 64 slices
            const int idx = bid * 64 + li;            // 512 blocks x 64 floats = v
            const float* p = sp + (size_t)kq * 16 * 32768 + idx;
            float a0 = 0.f, a1 = 0.f, a2 = 0.f, a3 = 0.f;
            #pragma unroll
            for (int k = 0; k < 16; k += 4) {
                a0 += p[(k + 0) * 32768];
                a1 += p[(k + 1) * 32768];
                a2 += p[(k + 2) * 32768];
                a3 += p[(k + 3) * 32768];
            }
            redr[t] = (a0 + a1) + (a2 + a3);
            __syncthreads();
            if (t < 64) {
                const float s2 = (redr[t] + redr[t + 64]) + (redr[t + 128] + redr[t + 192]);
                float* dst = (it < 2) ? v : out;
                dst[idx] = squashf(s2);
            }
        }
        if (it == 2) break;                           // out written -> done
        gbar(bar, it * 3 + 2);

        // ================= A: blog += <u_hat, v>/B; colsum bins =================
        {
            float* colbins = (it == 0) ? cs0 : cs1;
            const int w = t >> 6, lane = t & 63;
            const int co4 = lane, c = lane >> 2;
            const float4* __restrict__ V4 = (const float4*)v;

            for (int r = bid; r < R_; r += GRID_) {
                xla[t] = X4[((t >> 1) * R_ + r) * 2 + (t & 1)];
                __syncthreads();

                float y[8][4];
                #pragma unroll
                for (int i = 0; i < 8; ++i)
                    #pragma unroll
                    for (int q = 0; q < 4; ++q) y[i][q] = 0.f;

                const int b0 = w * 32;
                #pragma unroll 4
                for (int bb = 0; bb < 32; ++bb) {
                    const int b = b0 + bb;
                    const float4 xa = xla[b * 2];
                    const float4 xb = xla[b * 2 + 1];
                    const float4 vv = V4[b * 64 + co4];
                    y[0][0] = fmaf(xa.x, vv.x, y[0][0]); y[0][1] = fmaf(xa.x, vv.y, y[0][1]);
                    y[0][2] = fmaf(xa.x, vv.z, y[0][2]); y[0][3] = fmaf(xa.x, vv.w, y[0][3]);
                    y[1][0] = fmaf(xa.y, vv.x, y[1][0]); y[1][1] = fmaf(xa.y, vv.y, y[1][1]);
                    y[1][2] = fmaf(xa.y, vv.z, y[1][2]); y[1][3] = fmaf(xa.y, vv.w, y[1][3]);
                    y[2][0] = fmaf(xa.z, vv.x, y[2][0]); y[2][1] = fmaf(xa.z, vv.y, y[2][1]);
                    y[2][2] = fmaf(xa.z, vv.z, y[2][2]); y[2][3] = fmaf(xa.z, vv.w, y[2][3]);
                    y[3][0] = fmaf(xa.w, vv.x, y[3][0]); y[3][1] = fmaf(xa.w, vv.y, y[3][1]);
                    y[3][2] = fmaf(xa.w, vv.z, y[3][2]); y[3][3] = fmaf(xa.w, vv.w, y[3][3]);
                    y[4][0] = fmaf(xb.x, vv.x, y[4][0]); y[4][1] = fmaf(xb.x, vv.y, y[4][1]);
                    y[4][2] = fmaf(xb.x, vv.z, y[4][2]); y[4][3] = fmaf(xb.x, vv.w, y[4][3]);
                    y[5][0] = fmaf(xb.y, vv.x, y[5][0]); y[5][1] = fmaf(xb.y, vv.y, y[5][1]);
                    y[5][2] = fmaf(xb.y, vv.z, y[5][2]); y[5][3] = fmaf(xb.y, vv.w, y[5][3]);
                    y[6][0] = fmaf(xb.z, vv.x, y[6][0]); y[6][1] = fmaf(xb.z, vv.y, y[6][1]);
                    y[6][2] = fmaf(xb.z, vv.z, y[6][2]); y[6][3] = fmaf(xb.z, vv.w, y[6][3]);
                    y[7][0] = fmaf(xb.w, vv.x, y[7][0]); y[7][1] = fmaf(xb.w, vv.y, y[7][1]);
                    y[7][2] = fmaf(xb.w, vv.z, y[7][2]); y[7][3] = fmaf(xb.w, vv.w, y[7][3]);
                }

                const float4* wp = (const float4*)wt + ((size_t)r << 9) + co4;
                float part = 0.f;
                #pragma unroll
                for (int q = 0; q < 4; ++q) {
                    const float4 w0 = wp[(2 * q) * 64];
                    const float4 w1 = wp[(2 * q + 1) * 64];
                    part += w0.x*y[0][q] + w0.y*y[1][q] + w0.z*y[2][q] + w0.w*y[3][q]
                          + w1.x*y[4][q] + w1.y*y[5][q] + w1.z*y[6][q] + w1.w*y[7][q];
                }
                part += __shfl_xor(part, 1);
                part += __shfl_xor(part, 2);
                if ((lane & 3) == 0) reda[w * 16 + c] = part;
                __syncthreads();
                if (t < 16) {
                    const float val = ((reda[t] + reda[16 + t]) + (reda[32 + t] + reda[48 + t]))
                                      * (1.0f / (float)B_);
                    const int idx2 = r * 16 + t;
                    const float nv = (it == 0) ? val : (blog[idx2] + val);
                    blog[idx2] = nv;
                    atomicAdd(&colbins[(r >> 4) * 16 + t], __expf(nv));
                }
                __syncthreads();   // WAR: xla/reda reused next round
            }
        }
        gbar(bar, it * 3 + 3);
    }
}

extern "C" void kernel_launch(void* const* d_in, const int* in_sizes, int n_in,
                              void* d_out, int out_size, void* d_ws, size_t ws_size,
                              hipStream_t stream) {
    const float* x = (const float*)d_in[0];   // [128,1152,8]
    const float* W = (const float*)d_in[1];   // [1,1152,16,16,8]
    float* out = (float*)d_out;               // [128,16,16]
    float* ws  = (float*)d_ws;                // ~18 MB used

    float* sp   = ws + WS_SP;
    float* v    = ws + WS_V;
    float* blog = ws + WS_BLOG;
    float* ctrl = ws + WS_CTRL;
    float* wt   = ws + WS_WT;

    zero_k<<<1, 256, 0, stream>>>(ctrl);
    caps_all_k<<<GRID_, 256, 0, stream>>>(x, W, wt, sp, v, blog, ctrl, out);
}

// Round 8
// 167.361 us; speedup vs baseline: 4.4347x; 4.4347x over previous
//
#include <hip/hip_runtime.h>
#include <math.h>

#define B_   128
#define R_   1152
#define RS_  64
#define RCH_ 18            // R_/RS_
#define NBINS 72           // 1152/16 colsum bins

// ws float offsets
#define WS_SP   0          // RS_*32768 = 2097152
#define WS_V    2097152    // 32768
#define WS_BLOG 2129920    // 18432
#define WS_CTRL 2148352    // 2560 floats: cs0 bins @+0 (72*16), cs1 bins @+1280
#define WS_WT   2150912    // 2359296 (Wt4[r*512 + d*64 + co4])

__device__ __forceinline__ float squashf(float s) {
    return s * fabsf(s) / (1.0f + s * s);
}

// ---------- T: Wt4[r*512 + d*64 + co4] = W4[r*512 + co4*8 + d]  (pitch-65 LDS swizzle)
//             + zero the colsum bin area once per run
__global__ __launch_bounds__(512) void wtrans_k(const float* __restrict__ W,
                                                float* __restrict__ wt,
                                                float* __restrict__ ctrl) {
    const int r = blockIdx.x;
    const int t = threadIdx.x;
    __shared__ float4 sh[520];
    const float4* __restrict__ W4 = (const float4*)W;
    float4* __restrict__ Wt4 = (float4*)wt;

    if (r == 0) {
        for (int u = t; u < 2560; u += 512) ctrl[u] = 0.0f;
    }

    sh[(t & 7) * 65 + (t >> 3)] = W4[r * 512 + t];     // t = co4*8 + d
    __syncthreads();
    Wt4[r * 512 + t] = sh[(t >> 6) * 65 + (t & 63)];   // t = d*64 + co4
}

// ---------- G: sp[rs][b][co] = sum_{r in chunk,i} x[b,r,i]*cw[r,c]*W[r,co,i]
// grid dim3(16 bt, RS_ rs) x 256 — R6 body with 2x finer batch split:
// 1024 blocks = 4 blocks/CU = 16 waves/CU for L2-latency hiding (R6 ran 8).
// FIRST: cw = 1/R exactly. Else cw = exp(blog)*1/colsum from 72x16 bins.
template <bool FIRST>
__global__ __launch_bounds__(256) void gemm_s_k(const float* __restrict__ x,
                                                const float* __restrict__ wt,
                                                const float* __restrict__ blog,
                                                const float* __restrict__ colbins,
                                                float* __restrict__ sp) {
    const int bt  = blockIdx.x;           // 0..15 (8 b each)
    const int rs  = blockIdx.y;
    const int t   = threadIdx.x;
    const int co4 = t & 63;
    const int b4  = t >> 6;               // 0..3 (2 b each)
    const int c   = co4 >> 2;
    const int r0  = rs * RCH_;

    __shared__ float4 xl4[288];         // 8 b x 18 r x 2 f4 = 4.6 KB
    __shared__ float  cwl[RCH_ * 16];   // 288
    __shared__ float  colinv_sh[16];
    __shared__ float  psum[256];

    const float4* __restrict__ X4  = (const float4*)x;
    const float4* __restrict__ Wt4 = (const float4*)wt;

    // stage x tile: 8 b x 18 r x 2 f4
    #pragma unroll
    for (int k = 0; k < 2; ++k) {
        const int u = t + k * 256;
        if (u < 288) {
            const int bl = u / 36, rem = u % 36;
            xl4[u] = X4[((bt * 8 + bl) * R_ + r0) * 2 + rem];
        }
    }

    // prepass: colinv from bins (16 j-lanes x 16 cc), then cwl rows
    if (!FIRST) {
        const int cc = t & 15, jb = t >> 4;
        float s = 0.f;
        for (int j = jb; j < NBINS; j += 16) s += colbins[j * 16 + cc];
        psum[t] = s;
        __syncthreads();
        if (t < 16) {
            float tot = 0.f;
            #pragma unroll
            for (int k2 = 0; k2 < 16; ++k2) tot += psum[k2 * 16 + t];
            colinv_sh[t] = 1.0f / tot;
        }
        __syncthreads();
        for (int u2 = t; u2 < RCH_ * 16; u2 += 256) {
            const int rl = u2 >> 4, c2 = u2 & 15;
            cwl[u2] = __expf(blog[(r0 + rl) * 16 + c2]) * colinv_sh[c2];
        }
    }
    __syncthreads();

    float acc[2][4];
    #pragma unroll
    for (int j = 0; j < 2; ++j)
        #pragma unroll
        for (int q = 0; q < 4; ++q) acc[j][q] = 0.f;

    // R6-identical hot loop structure (named w0..w7, unroll 3), j-extent 2
    #pragma unroll 3
    for (int rr = 0; rr < RCH_; ++rr) {
        const float cwv = FIRST ? (1.0f / (float)R_) : cwl[rr * 16 + c];
        const float4* wp = Wt4 + ((size_t)(r0 + rr) << 9) + co4;   // lane-stride 16B
        const float4 w0 = wp[  0], w1 = wp[ 64], w2 = wp[128], w3 = wp[192];
        const float4 w4 = wp[256], w5 = wp[320], w6 = wp[384], w7 = wp[448];
        #pragma unroll
        for (int j = 0; j < 2; ++j) {
            const float4 xa = xl4[(b4 * 2 + j) * 36 + rr * 2];
            const float4 xb = xl4[(b4 * 2 + j) * 36 + rr * 2 + 1];
            const float d0 = w0.x*xa.x + w0.y*xa.y + w0.z*xa.z + w0.w*xa.w
                           + w1.x*xb.x + w1.y*xb.y + w1.z*xb.z + w1.w*xb.w;
            const float d1 = w2.x*xa.x + w2.y*xa.y + w2.z*xa.z + w2.w*xa.w
                           + w3.x*xb.x + w3.y*xb.y + w3.z*xb.z + w3.w*xb.w;
            const float d2 = w4.x*xa.x + w4.y*xa.y + w4.z*xa.z + w4.w*xa.w
                           + w5.x*xb.x + w5.y*xb.y + w5.z*xb.z + w5.w*xb.w;
            const float d3 = w6.x*xa.x + w6.y*xa.y + w6.z*xa.z + w6.w*xa.w
                           + w7.x*xb.x + w7.y*xb.y + w7.z*xb.z + w7.w*xb.w;
            acc[j][0] = fmaf(cwv, d0, acc[j][0]);
            acc[j][1] = fmaf(cwv, d1, acc[j][1]);
            acc[j][2] = fmaf(cwv, d2, acc[j][2]);
            acc[j][3] = fmaf(cwv, d3, acc[j][3]);
        }
    }

    float4* sp4 = (float4*)sp;
    #pragma unroll
    for (int j = 0; j < 2; ++j) {
        const int b = bt * 8 + b4 * 2 + j;
        float4 o4; o4.x = acc[j][0]; o4.y = acc[j][1]; o4.z = acc[j][2]; o4.w = acc[j][3];
        sp4[(rs * B_ + b) * 64 + co4] = o4;
    }
}

// ---------- R: v[b,co] = squash(sum_k sp[k][b][co]); grid 256 x 512 (R6-identical)
__global__ __launch_bounds__(512) void reduce_squash_k(const float* __restrict__ sp,
                                                       float* __restrict__ outv) {
    const int t   = threadIdx.x;
    const int li  = t & 127;
    const int kq  = t >> 7;               // 0..3 (16 slices each)
    const int idx = blockIdx.x * 128 + li;
    const float* p = sp + (size_t)kq * 16 * 32768 + idx;
    float a0 = 0.f, a1 = 0.f, a2 = 0.f, a3 = 0.f;
    #pragma unroll
    for (int k = 0; k < 16; k += 4) {
        a0 += p[(k + 0) * 32768];
        a1 += p[(k + 1) * 32768];
        a2 += p[(k + 2) * 32768];
        a3 += p[(k + 3) * 32768];
    }
    __shared__ float red[512];
    red[t] = (a0 + a1) + (a2 + a3);
    __syncthreads();
    if (t < 128) {
        const float s = (red[t] + red[t + 128]) + (red[t + 256] + red[t + 384]);
        outv[idx] = squashf(s);
    }
}

// ---------- A: blog[r,c] (+)= (1/B) sum_{b,o} u_hat[b,r,co]*v[b,co] ----------
// R6-identical: grid 1152 x 256 (1 r/block; 4 waves = batch quarters),
// launch_bounds(256,2) keeps y[8][4] in registers; 72x16 colsum bins.
template <bool FIRST>
__global__ __launch_bounds__(256, 2) void a_k(const float* __restrict__ x,
                                              const float* __restrict__ wt,
                                              const float* __restrict__ v,
                                              float* __restrict__ blog,
                                              float* __restrict__ colbins) {
    const int r = blockIdx.x;
    const int t = threadIdx.x;
    const int w = t >> 6, lane = t & 63;
    const int co4 = lane, c = lane >> 2;

    __shared__ float4 xl[256];            // 128 b x 2 f4 = 4 KB
    __shared__ float  red[64];
    const float4* __restrict__ X4  = (const float4*)x;
    const float4* __restrict__ V4  = (const float4*)v;
    const float4* __restrict__ Wt4 = (const float4*)wt;

    xl[t] = X4[((t >> 1) * R_ + r) * 2 + (t & 1)];
    __syncthreads();

    float y[8][4];
    #pragma unroll
    for (int i = 0; i < 8; ++i)
        #pragma unroll
        for (int q = 0; q < 4; ++q) y[i][q] = 0.f;

    const int b0 = w * 32;
    #pragma unroll 4
    for (int bb = 0; bb < 32; ++bb) {
        const int b = b0 + bb;
        const float4 xa = xl[b * 2];
        const float4 xb = xl[b * 2 + 1];
        const float4 vv = V4[b * 64 + co4];
        y[0][0] = fmaf(xa.x, vv.x, y[0][0]); y[0][1] = fmaf(xa.x, vv.y, y[0][1]);
        y[0][2] = fmaf(xa.x, vv.z, y[0][2]); y[0][3] = fmaf(xa.x, vv.w, y[0][3]);
        y[1][0] = fmaf(xa.y, vv.x, y[1][0]); y[1][1] = fmaf(xa.y, vv.y, y[1][1]);
        y[1][2] = fmaf(xa.y, vv.z, y[1][2]); y[1][3] = fmaf(xa.y, vv.w, y[1][3]);
        y[2][0] = fmaf(xa.z, vv.x, y[2][0]); y[2][1] = fmaf(xa.z, vv.y, y[2][1]);
        y[2][2] = fmaf(xa.z, vv.z, y[2][2]); y[2][3] = fmaf(xa.z, vv.w, y[2][3]);
        y[3][0] = fmaf(xa.w, vv.x, y[3][0]); y[3][1] = fmaf(xa.w, vv.y, y[3][1]);
        y[3][2] = fmaf(xa.w, vv.z, y[3][2]); y[3][3] = fmaf(xa.w, vv.w, y[3][3]);
        y[4][0] = fmaf(xb.x, vv.x, y[4][0]); y[4][1] = fmaf(xb.x, vv.y, y[4][1]);
        y[4][2] = fmaf(xb.x, vv.z, y[4][2]); y[4][3] = fmaf(xb.x, vv.w, y[4][3]);
        y[5][0] = fmaf(xb.y, vv.x, y[5][0]); y[5][1] = fmaf(xb.y, vv.y, y[5][1]);
        y[5][2] = fmaf(xb.y, vv.z, y[5][2]); y[5][3] = fmaf(xb.y, vv.w, y[5][3]);
        y[6][0] = fmaf(xb.z, vv.x, y[6][0]); y[6][1] = fmaf(xb.z, vv.y, y[6][1]);
        y[6][2] = fmaf(xb.z, vv.z, y[6][2]); y[6][3] = fmaf(xb.z, vv.w, y[6][3]);
        y[7][0] = fmaf(xb.w, vv.x, y[7][0]); y[7][1] = fmaf(xb.w, vv.y, y[7][1]);
        y[7][2] = fmaf(xb.w, vv.z, y[7][2]); y[7][3] = fmaf(xb.w, vv.w, y[7][3]);
    }

    const float4* wp = Wt4 + ((size_t)r << 9) + co4;
    float part = 0.f;
    #pragma unroll
    for (int q = 0; q < 4; ++q) {
        const float4 w0 = wp[(2 * q) * 64];
        const float4 w1 = wp[(2 * q + 1) * 64];
        part += w0.x*y[0][q] + w0.y*y[1][q] + w0.z*y[2][q] + w0.w*y[3][q]
              + w1.x*y[4][q] + w1.y*y[5][q] + w1.z*y[6][q] + w1.w*y[7][q];
    }
    part += __shfl_xor(part, 1);
    part += __shfl_xor(part, 2);
    if ((lane & 3) == 0) red[w * 16 + c] = part;
    __syncthreads();
    if (t < 16) {
        const float val = ((red[t] + red[16 + t]) + (red[32 + t] + red[48 + t]))
                          * (1.0f / (float)B_);
        const int idx = r * 16 + t;
        const float nv = FIRST ? val : (blog[idx] + val);
        blog[idx] = nv;
        atomicAdd(&colbins[(r >> 4) * 16 + t], __expf(nv));  // 16-deep chains
    }
}

extern "C" void kernel_launch(void* const* d_in, const int* in_sizes, int n_in,
                              void* d_out, int out_size, void* d_ws, size_t ws_size,
                              hipStream_t stream) {
    const float* x = (const float*)d_in[0];   // [128,1152,8]
    const float* W = (const float*)d_in[1];   // [1,1152,16,16,8]
    float* out = (float*)d_out;               // [128,16,16]
    float* ws  = (float*)d_ws;                // ~18 MB used

    float* sp   = ws + WS_SP;
    float* v    = ws + WS_V;
    float* blog = ws + WS_BLOG;
    float* ctrl = ws + WS_CTRL;
    float* wt   = ws + WS_WT;

    float* cs0 = ctrl;                        // 72x16 bins
    float* cs1 = ctrl + 1280;                 // 72x16 bins

    // build Wt once (coalesced transpose) + zero colsum bins
    wtrans_k<<<R_, 512, 0, stream>>>(W, wt, ctrl);

    // iter 0 (softmax(0) == 1/R exactly)
    gemm_s_k<true ><<<dim3(16, RS_), 256, 0, stream>>>(x, wt, nullptr, nullptr, sp);
    reduce_squash_k<<<256, 512, 0, stream>>>(sp, v);
    a_k<true ><<<R_, 256, 0, stream>>>(x, wt, v, blog, cs0);

    // iter 1
    gemm_s_k<false><<<dim3(16, RS_), 256, 0, stream>>>(x, wt, blog, cs0, sp);
    reduce_squash_k<<<256, 512, 0, stream>>>(sp, v);
    a_k<false><<<R_, 256, 0, stream>>>(x, wt, v, blog, cs1);

    // iter 2
    gemm_s_k<false><<<dim3(16, RS_), 256, 0, stream>>>(x, wt, blog, cs1, sp);
    reduce_squash_k<<<256, 512, 0, stream>>>(sp, out);
}